// Round 3
// baseline (408.403 us; speedup 1.0000x reference)
//
#include <hip/hip_runtime.h>

typedef __bf16 bf16x8 __attribute__((ext_vector_type(8)));
typedef float f32x4 __attribute__((ext_vector_type(4)));
typedef unsigned short u16;

__device__ inline u16 f2bf(float f) {
  union { float f; unsigned int u; } v; v.f = f;
  unsigned int r = v.u + 0x7fffu + ((v.u >> 16) & 1u);
  return (u16)(r >> 16);
}

__device__ inline void load_lds16(const void* g, void* l) {
  __builtin_amdgcn_global_load_lds((const __attribute__((address_space(1))) unsigned int*)g,
                                   (__attribute__((address_space(3))) unsigned int*)l, 16, 0, 0);
}

__device__ inline float rmax16(float v) {
  v = fmaxf(v, __shfl_xor(v, 1, 16));
  v = fmaxf(v, __shfl_xor(v, 2, 16));
  v = fmaxf(v, __shfl_xor(v, 4, 16));
  v = fmaxf(v, __shfl_xor(v, 8, 16));
  return v;
}
__device__ inline float rsum16(float v) {
  v += __shfl_xor(v, 1, 16);
  v += __shfl_xor(v, 2, 16);
  v += __shfl_xor(v, 4, 16);
  v += __shfl_xor(v, 8, 16);
  return v;
}

// ---------------- prepass: fp32 -> bf16 ----------------
__global__ void cvt_bf16(const float* __restrict__ in, u16* __restrict__ out, int n) {
  int i = (blockIdx.x * blockDim.x + threadIdx.x) * 4;
  if (i < n) {
    float4 v = *(const float4*)(in + i);
    ushort4 o;
    o.x = f2bf(v.x); o.y = f2bf(v.y); o.z = f2bf(v.z); o.w = f2bf(v.w);
    *(ushort4*)(out + i) = o;
  }
}

// in [R][C] fp32 -> out [C][R] bf16
__global__ void transpose_cvt(const float* __restrict__ in, u16* __restrict__ out, int R, int C) {
  __shared__ float tile[32][33];
  int c0 = blockIdx.x * 32, r0 = blockIdx.y * 32;
  int tx = threadIdx.x;
#pragma unroll
  for (int i = threadIdx.y; i < 32; i += 8)
    tile[i][tx] = in[(size_t)(r0 + i) * C + c0 + tx];
  __syncthreads();
#pragma unroll
  for (int i = threadIdx.y; i < 32; i += 8)
    out[(size_t)(c0 + i) * R + r0 + tx] = f2bf(tile[tx][i]);
}

// V transpose: vT[h][d][s] from qkv[s][1536 + h*64 + d]
__global__ __launch_bounds__(256) void vtrans(const u16* __restrict__ qkv, u16* __restrict__ vT) {
  const int h = blockIdx.y;
  const int s0 = blockIdx.x * 64;
  const int tid = threadIdx.x;
  __shared__ u16 T[64][72];
  {
    const int key = tid >> 2, dq = (tid & 3) * 16;
    const u16* g = qkv + (size_t)(s0 + key) * 2304 + 1536 + h * 64 + dq;
    *(uint4*)&T[key][dq] = *(const uint4*)g;
    *(uint4*)&T[key][dq + 8] = *(const uint4*)(g + 8);
  }
  __syncthreads();
  {
    const int d = tid >> 2, sq = (tid & 3) * 16;
    u16 tmp[16];
#pragma unroll
    for (int e = 0; e < 16; ++e) tmp[e] = T[sq + e][d];
    u16* o = vT + ((size_t)h * 64 + d) * 4096 + s0 + sq;
    *(uint4*)o = *(uint4*)tmp;
    *(uint4*)(o + 8) = *(uint4*)(tmp + 8);
  }
}

// ---------------- GEMM: C = A[M,K] * BT[N,K]^T + bias, bf16 in ----------------
template <int BF16_OUT>
__global__ __launch_bounds__(256) void gemm_bt(const u16* __restrict__ A, const u16* __restrict__ BT,
                                               const float* __restrict__ bias, void* __restrict__ Cv,
                                               int M, int N, int K) {
  __shared__ __align__(16) u16 As[128 * 32];
  __shared__ __align__(16) u16 Bs[128 * 32];
  const int tid = threadIdx.x;
  const int wave = tid >> 6, lane = tid & 63;
  const int g = lane >> 4, lr = lane & 15;
  const int m0 = blockIdx.y * 128, n0 = blockIdx.x * 128;
  const int wr = (wave >> 1) * 64, wc = (wave & 1) * 64;
  f32x4 acc[4][4] = {};

  for (int k0 = 0; k0 < K; k0 += 32) {
    __syncthreads();
#pragma unroll
    for (int j = 0; j < 2; ++j) {
      const int e = tid * 8 + j * 2048;
      const int r = e >> 5, c = e & 31;
      const u16* ga = A + (size_t)(m0 + r) * K + k0 + c;
      const u16* gb = BT + (size_t)(n0 + r) * K + k0 + c;
      load_lds16(ga, (void*)(As + wave * 512 + j * 2048));
      load_lds16(gb, (void*)(Bs + wave * 512 + j * 2048));
    }
    __syncthreads();
    const u16* pa = As + (wr + lr) * 32 + g * 8;
    const u16* pb = Bs + (wc + lr) * 32 + g * 8;
    bf16x8 a[4], b[4];
#pragma unroll
    for (int i = 0; i < 4; ++i) a[i] = *(const bf16x8*)(pa + i * 16 * 32);
#pragma unroll
    for (int j = 0; j < 4; ++j) b[j] = *(const bf16x8*)(pb + j * 16 * 32);
#pragma unroll
    for (int i = 0; i < 4; ++i)
#pragma unroll
      for (int j = 0; j < 4; ++j)
        acc[i][j] = __builtin_amdgcn_mfma_f32_16x16x32_bf16(a[i], b[j], acc[i][j], 0, 0, 0);
  }

#pragma unroll
  for (int i = 0; i < 4; ++i)
#pragma unroll
    for (int j = 0; j < 4; ++j)
#pragma unroll
      for (int r = 0; r < 4; ++r) {
        int row = m0 + wr + i * 16 + g * 4 + r;
        int col = n0 + wc + j * 16 + lr;
        float v = acc[i][j][r] + bias[col];
        if (BF16_OUT)
          ((u16*)Cv)[(size_t)row * N + col] = f2bf(v);
        else
          ((float*)Cv)[(size_t)row * N + col] = v;
      }
}

// ---------------- causal flash attention, barrier-free ----------------
// qkv: [4096][2304] bf16 (q|k|v), vT: [12][64][4096] bf16. out a: [4096][768] bf16
// 256 threads = 4 waves; each wave owns 16 q-rows; Q-tile = 64 rows; KV-tile = 64 keys.
// No __syncthreads: K and V^T fragments load directly from global (L1/L2-resident),
// only the wave-private P round-trip uses LDS.
__global__ __launch_bounds__(256, 3) void attn(const u16* __restrict__ qkv, const u16* __restrict__ vT,
                                               u16* __restrict__ aout) {
  const int h = blockIdx.y;
  const int qt = (int)gridDim.x - 1 - (int)blockIdx.x;  // heavy blocks first
  const int q0 = qt * 64;
  const int tid = threadIdx.x;
  const int wave = tid >> 6, lane = tid & 63;
  const int g = lane >> 4, lr = lane & 15;

  __shared__ __align__(16) u16 Ps[4][16 * 72];  // per-wave P tile [row][key]

  const int qrow_base = q0 + wave * 16;
  const u16* kbase = qkv + 768 + h * 64 + (size_t)0;
  const u16* vbase = vT + (size_t)h * 64 * 4096;

  // Q fragments (A-layout): row = lr, k = dim
  bf16x8 qf[2];
#pragma unroll
  for (int kb = 0; kb < 2; ++kb)
    qf[kb] = *(const bf16x8*)(qkv + (size_t)(qrow_base + lr) * 2304 + h * 64 + kb * 32 + g * 8);

  f32x4 O[4] = {};
  float mst[4], lst[4];
#pragma unroll
  for (int r = 0; r < 4; ++r) { mst[r] = -__builtin_inff(); lst[r] = 0.f; }

  const int nkt_w = ((qrow_base + 15) >> 6) + 1;  // K-tiles this wave needs

  for (int t = 0; t < nkt_w; ++t) {
    const int kk0 = t * 64;

    // S = Q * K^T  (K fragments direct from global: row=key, k-contiguous)
    bf16x8 kf[4][2];
#pragma unroll
    for (int cb = 0; cb < 4; ++cb)
#pragma unroll
      for (int kb = 0; kb < 2; ++kb)
        kf[cb][kb] = *(const bf16x8*)(kbase + (size_t)(kk0 + cb * 16 + lr) * 2304 + kb * 32 + g * 8);

    // V^T fragments direct from global: row=dim, key-contiguous
    bf16x8 vb[4][2];
#pragma unroll
    for (int cb = 0; cb < 4; ++cb)
#pragma unroll
      for (int k2 = 0; k2 < 2; ++k2)
        vb[cb][k2] = *(const bf16x8*)(vbase + (size_t)(cb * 16 + lr) * 4096 + kk0 + k2 * 32 + g * 8);

    f32x4 s[4] = {};
#pragma unroll
    for (int cb = 0; cb < 4; ++cb)
#pragma unroll
      for (int kb = 0; kb < 2; ++kb)
        s[cb] = __builtin_amdgcn_mfma_f32_16x16x32_bf16(qf[kb], kf[cb][kb], s[cb], 0, 0, 0);

    const bool needmask = (kk0 + 63 > qrow_base);

    // online softmax: rows g*4+r live in lane group g across lr
#pragma unroll
    for (int r = 0; r < 4; ++r) {
      const int qrow = qrow_base + g * 4 + r;
      float sv[4];
#pragma unroll
      for (int cb = 0; cb < 4; ++cb) {
        float v = s[cb][r] * 0.125f;
        if (needmask) {
          const int kcol = kk0 + cb * 16 + lr;
          if (kcol > qrow) v = -__builtin_inff();
        }
        sv[cb] = v;
      }
      float mx = fmaxf(fmaxf(sv[0], sv[1]), fmaxf(sv[2], sv[3]));
      mx = rmax16(mx);
      const float mo = mst[r];
      const float mn = fmaxf(mo, mx);
      const float alpha = __expf(mo - mn);
      float rs = 0.f;
      float pv[4];
#pragma unroll
      for (int cb = 0; cb < 4; ++cb) { pv[cb] = __expf(sv[cb] - mn); rs += pv[cb]; }
      rs = rsum16(rs);
      lst[r] = lst[r] * alpha + rs;
      mst[r] = mn;
#pragma unroll
      for (int cb = 0; cb < 4; ++cb) O[cb][r] *= alpha;
#pragma unroll
      for (int cb = 0; cb < 4; ++cb)
        Ps[wave][(g * 4 + r) * 72 + cb * 16 + lr] = f2bf(pv[cb]);
    }
    asm volatile("s_waitcnt lgkmcnt(0)" ::: "memory");
    __builtin_amdgcn_sched_barrier(0);

    // O += P * V
    bf16x8 pa[2];
#pragma unroll
    for (int k2 = 0; k2 < 2; ++k2)
      pa[k2] = *(const bf16x8*)&Ps[wave][lr * 72 + k2 * 32 + g * 8];
#pragma unroll
    for (int cb = 0; cb < 4; ++cb)
#pragma unroll
      for (int k2 = 0; k2 < 2; ++k2)
        O[cb] = __builtin_amdgcn_mfma_f32_16x16x32_bf16(pa[k2], vb[cb][k2], O[cb], 0, 0, 0);
  }

  // epilogue: divide by l, store bf16
#pragma unroll
  for (int r = 0; r < 4; ++r) {
    const int row = qrow_base + g * 4 + r;
    const float inv = 1.0f / lst[r];
#pragma unroll
    for (int cb = 0; cb < 4; ++cb)
      aout[(size_t)row * 768 + h * 64 + cb * 16 + lr] = f2bf(O[cb][r] * inv);
  }
}

// ---------------- launch ----------------
extern "C" void kernel_launch(void* const* d_in, const int* in_sizes, int n_in,
                              void* d_out, int out_size, void* d_ws, size_t ws_size,
                              hipStream_t stream) {
  const float* x = (const float*)d_in[0];
  const float* w_attn = (const float*)d_in[1];
  const float* b_attn = (const float*)d_in[2];
  const float* w_proj = (const float*)d_in[3];
  const float* b_proj = (const float*)d_in[4];
  float* out = (float*)d_out;

  const int S = 4096, D = 768;
  u16* xb = (u16*)d_ws;                 // [4096][768]
  u16* wTa = xb + (size_t)S * D;        // [2304][768]
  u16* wTp = wTa + (size_t)3 * D * D;   // [768][768]
  u16* qkv = wTp + (size_t)D * D;       // [4096][2304]
  u16* abuf = qkv + (size_t)S * 3 * D;  // [4096][768]
  u16* vTb = abuf + (size_t)S * D;      // [12][64][4096]

  cvt_bf16<<<(S * D) / 1024, 256, 0, stream>>>(x, xb, S * D);
  transpose_cvt<<<dim3((3 * D) / 32, D / 32), dim3(32, 8), 0, stream>>>(w_attn, wTa, D, 3 * D);
  transpose_cvt<<<dim3(D / 32, D / 32), dim3(32, 8), 0, stream>>>(w_proj, wTp, D, D);
  gemm_bt<1><<<dim3((3 * D) / 128, S / 128), 256, 0, stream>>>(xb, wTa, b_attn, qkv, S, 3 * D, D);
  vtrans<<<dim3(S / 64, 12), 256, 0, stream>>>(qkv, vTb);
  attn<<<dim3(S / 64, 12), 256, 0, stream>>>(qkv, vTb, abuf);
  gemm_bt<0><<<dim3(D / 128, S / 128), 256, 0, stream>>>(abuf, wTp, b_proj, out, S, D, D);
}

// Round 5
// 175.500 us; speedup vs baseline: 2.3271x; 2.3271x over previous
//
#include <hip/hip_runtime.h>

typedef __bf16 bf16x8 __attribute__((ext_vector_type(8)));
typedef float f32x4 __attribute__((ext_vector_type(4)));
typedef unsigned short u16;

__device__ inline u16 f2bf(float f) {
  union { float f; unsigned int u; } v; v.f = f;
  unsigned int r = v.u + 0x7fffu + ((v.u >> 16) & 1u);
  return (u16)(r >> 16);
}

__device__ inline void load_lds16(const void* g, void* l) {
  __builtin_amdgcn_global_load_lds((const __attribute__((address_space(1))) unsigned int*)g,
                                   (__attribute__((address_space(3))) unsigned int*)l, 16, 0, 0);
}

// ---------------- prepass: fp32 -> bf16 ----------------
__global__ void cvt_bf16(const float* __restrict__ in, u16* __restrict__ out, int n) {
  int i = (blockIdx.x * blockDim.x + threadIdx.x) * 4;
  if (i < n) {
    float4 v = *(const float4*)(in + i);
    ushort4 o;
    o.x = f2bf(v.x); o.y = f2bf(v.y); o.z = f2bf(v.z); o.w = f2bf(v.w);
    *(ushort4*)(out + i) = o;
  }
}

// in [R][C] fp32 -> out [C][R] bf16
__global__ void transpose_cvt(const float* __restrict__ in, u16* __restrict__ out, int R, int C) {
  __shared__ float tile[32][33];
  int c0 = blockIdx.x * 32, r0 = blockIdx.y * 32;
  int tx = threadIdx.x;
#pragma unroll
  for (int i = threadIdx.y; i < 32; i += 8)
    tile[i][tx] = in[(size_t)(r0 + i) * C + c0 + tx];
  __syncthreads();
#pragma unroll
  for (int i = threadIdx.y; i < 32; i += 8)
    out[(size_t)(c0 + i) * R + r0 + tx] = f2bf(tile[tx][i]);
}

// V transpose: vT[h][d][s] from qkv[s][1536 + h*64 + d]
__global__ __launch_bounds__(256) void vtrans(const u16* __restrict__ qkv, u16* __restrict__ vT) {
  const int h = blockIdx.y;
  const int s0 = blockIdx.x * 64;
  const int tid = threadIdx.x;
  __shared__ u16 T[64][72];
  {
    const int key = tid >> 2, dq = (tid & 3) * 16;
    const u16* g = qkv + (size_t)(s0 + key) * 2304 + 1536 + h * 64 + dq;
    *(uint4*)&T[key][dq] = *(const uint4*)g;
    *(uint4*)&T[key][dq + 8] = *(const uint4*)(g + 8);
  }
  __syncthreads();
  {
    const int d = tid >> 2, sq = (tid & 3) * 16;
    u16 tmp[16];
#pragma unroll
    for (int e = 0; e < 16; ++e) tmp[e] = T[sq + e][d];
    u16* o = vT + ((size_t)h * 64 + d) * 4096 + s0 + sq;
    *(uint4*)o = *(uint4*)tmp;
    *(uint4*)(o + 8) = *(uint4*)(tmp + 8);
  }
}

// ---------------- GEMM: C = A[M,K] * BT[N,K]^T + bias, bf16 in ----------------
template <int BF16_OUT>
__global__ __launch_bounds__(256) void gemm_bt(const u16* __restrict__ A, const u16* __restrict__ BT,
                                               const float* __restrict__ bias, void* __restrict__ Cv,
                                               int M, int N, int K) {
  __shared__ __align__(16) u16 As[128 * 32];
  __shared__ __align__(16) u16 Bs[128 * 32];
  const int tid = threadIdx.x;
  const int wave = tid >> 6, lane = tid & 63;
  const int g = lane >> 4, lr = lane & 15;
  const int m0 = blockIdx.y * 128, n0 = blockIdx.x * 128;
  const int wr = (wave >> 1) * 64, wc = (wave & 1) * 64;
  f32x4 acc[4][4] = {};

  for (int k0 = 0; k0 < K; k0 += 32) {
    __syncthreads();
#pragma unroll
    for (int j = 0; j < 2; ++j) {
      const int e = tid * 8 + j * 2048;
      const int r = e >> 5, c = e & 31;
      const u16* ga = A + (size_t)(m0 + r) * K + k0 + c;
      const u16* gb = BT + (size_t)(n0 + r) * K + k0 + c;
      load_lds16(ga, (void*)(As + wave * 512 + j * 2048));
      load_lds16(gb, (void*)(Bs + wave * 512 + j * 2048));
    }
    __syncthreads();
    const u16* pa = As + (wr + lr) * 32 + g * 8;
    const u16* pb = Bs + (wc + lr) * 32 + g * 8;
    bf16x8 a[4], b[4];
#pragma unroll
    for (int i = 0; i < 4; ++i) a[i] = *(const bf16x8*)(pa + i * 16 * 32);
#pragma unroll
    for (int j = 0; j < 4; ++j) b[j] = *(const bf16x8*)(pb + j * 16 * 32);
#pragma unroll
    for (int i = 0; i < 4; ++i)
#pragma unroll
      for (int j = 0; j < 4; ++j)
        acc[i][j] = __builtin_amdgcn_mfma_f32_16x16x32_bf16(a[i], b[j], acc[i][j], 0, 0, 0);
  }

#pragma unroll
  for (int i = 0; i < 4; ++i)
#pragma unroll
    for (int j = 0; j < 4; ++j)
#pragma unroll
      for (int r = 0; r < 4; ++r) {
        int row = m0 + wr + i * 16 + g * 4 + r;
        int col = n0 + wc + j * 16 + lr;
        float v = acc[i][j][r] + bias[col];
        if (BF16_OUT)
          ((u16*)Cv)[(size_t)row * N + col] = f2bf(v);
        else
          ((float*)Cv)[(size_t)row * N + col] = v;
      }
}

// ---------------- causal flash attention: swapped-QK in-register softmax ----------------
// qkv: [4096][2304] bf16 (q|k|v), vT: [12][64][4096] bf16. out a: [4096][768] bf16
// 4 waves x 16 q-rows = 64-row Q-tile; 64-key KV tiles; double-buffered LDS staging
// via global_load_lds with pre-swizzled source (XOR ((row&7)<<4) byte swizzle).
// Launched with a FLAT 1-D grid of 768 blocks (12 heads x 64 q-tiles).
__global__ __launch_bounds__(256, 3) void attn(const u16* __restrict__ qkv, const u16* __restrict__ vT,
                                               u16* __restrict__ aout) {
  __shared__ __align__(16) u16 Kb[2][4096];  // [key][dim] swizzled, 64x64
  __shared__ __align__(16) u16 Vb[2][4096];  // [dim][key] swizzled, 64x64

  const int bid = blockIdx.x;
  const int wid = (bid & 7) * 96 + (bid >> 3);  // XCD swizzle (768 % 8 == 0)
  const int h = wid >> 6;                       // head 0..11
  const int qt = 63 - (wid & 63);               // heavy diagonal blocks first
  const int q0 = qt * 64;

  const int tid = threadIdx.x;
  const int wave = tid >> 6, lane = tid & 63;
  const int g = lane >> 4, lr = lane & 15;
  const int g4 = g * 4;
  const int swz = (lr & 7) << 3;  // element swizzle for ds_read

  const int qrow_base = q0 + wave * 16;
  const u16* kgb = qkv + 768 + h * 64;
  const u16* vgb = vT + (size_t)h * 64 * 4096;

  // staging source map (per lane): key/dim sub-row l3, 16B chunk l7, swizzled chunk
  const int l3 = lane >> 3, l7 = lane & 7;
  const int ssw = ((l7 ^ l3) << 3);  // element offset of swizzled 16B chunk

  // Q fragments (B-operand): lane lr = q-row, elems = dims kb*32+g*8..+7; pre-scaled by 1/8
  bf16x8 qf[2];
#pragma unroll
  for (int kb = 0; kb < 2; ++kb) {
    bf16x8 raw = *(const bf16x8*)(qkv + (size_t)(qrow_base + lr) * 2304 + h * 64 + kb * 32 + g * 8);
#pragma unroll
    for (int e = 0; e < 8; ++e) qf[kb][e] = (__bf16)((float)raw[e] * 0.125f);
  }

  f32x4 O[4] = {};
  float mst = -__builtin_inff(), lst = 0.f;  // per-lane state for q-row (qrow_base + lr)

  const int nkt = qt + 1;

  // prologue: stage tile 0 (each wave issues 2 K + 2 V loads)
#pragma unroll
  for (int i = 0; i < 2; ++i) {
    const int j = wave * 2 + i;
    load_lds16(kgb + (size_t)(j * 8 + l3) * 2304 + ssw, Kb[0] + j * 512);
    load_lds16(vgb + (size_t)(j * 8 + l3) * 4096 + 0 + ssw, Vb[0] + j * 512);
  }

  int cur = 0;
  for (int t = 0; t < nkt; ++t) {
    if (t + 1 < nkt) {
      const int kk1 = (t + 1) * 64;
#pragma unroll
      for (int i = 0; i < 2; ++i) {
        const int j = wave * 2 + i;
        load_lds16(kgb + (size_t)(kk1 + j * 8 + l3) * 2304 + ssw, Kb[cur ^ 1] + j * 512);
        load_lds16(vgb + (size_t)(j * 8 + l3) * 4096 + kk1 + ssw, Vb[cur ^ 1] + j * 512);
      }
      asm volatile("s_waitcnt vmcnt(4)" ::: "memory");
    } else {
      asm volatile("s_waitcnt vmcnt(0)" ::: "memory");
    }
    __builtin_amdgcn_s_barrier();
    __builtin_amdgcn_sched_barrier(0);

    const u16* Kc = Kb[cur];
    const u16* Vc = Vb[cur];

    // S^T = K * Q^T : s[cb][r] = S[key kk0+cb*16+g4+r][qrow lr]
    f32x4 s[4] = {};
#pragma unroll
    for (int cb = 0; cb < 4; ++cb)
#pragma unroll
      for (int kb = 0; kb < 2; ++kb) {
        bf16x8 kf = *(const bf16x8*)(Kc + (cb * 16 + lr) * 64 + ((kb * 32 + g * 8) ^ swz));
        s[cb] = __builtin_amdgcn_mfma_f32_16x16x32_bf16(kf, qf[kb], s[cb], 0, 0, 0);
      }

    // V^T fragments (B-operand for PV): row = dim cb*16+lr, elems = keys k2*32+g*8..+7
    bf16x8 vbr[4][2];
#pragma unroll
    for (int cb = 0; cb < 4; ++cb)
#pragma unroll
      for (int k2 = 0; k2 < 2; ++k2)
        vbr[cb][k2] = *(const bf16x8*)(Vc + (cb * 16 + lr) * 64 + ((k2 * 32 + g * 8) ^ swz));

    // mask (diagonal tile only)
    if (t == nkt - 1) {
      const int rowloc = wave * 16 + lr;
#pragma unroll
      for (int cb = 0; cb < 4; ++cb)
#pragma unroll
        for (int r = 0; r < 4; ++r)
          if (cb * 16 + g4 + r > rowloc) s[cb][r] = -__builtin_inff();
    }

    // in-register online softmax for q-row lr
    float mx = s[0][0];
#pragma unroll
    for (int cb = 0; cb < 4; ++cb)
#pragma unroll
      for (int r = 0; r < 4; ++r) mx = fmaxf(mx, s[cb][r]);
    mx = fmaxf(mx, __shfl_xor(mx, 16));
    mx = fmaxf(mx, __shfl_xor(mx, 32));
    const float mn = fmaxf(mst, mx);
    const float alpha = __expf(mst - mn);
    mst = mn;
    float rs = 0.f;
#pragma unroll
    for (int cb = 0; cb < 4; ++cb)
#pragma unroll
      for (int r = 0; r < 4; ++r) {
        float p = __expf(s[cb][r] - mn);
        s[cb][r] = p;
        rs += p;
      }
    rs += __shfl_xor(rs, 16);
    rs += __shfl_xor(rs, 32);
    lst = lst * alpha + rs;

    // rescale O (alpha redistributed to row g4+r layout)
#pragma unroll
    for (int r = 0; r < 4; ++r) {
      const float ar = __shfl(alpha, (g << 4) + g4 + r, 64);
#pragma unroll
      for (int cb = 0; cb < 4; ++cb) O[cb][r] *= ar;
    }

    // pack P pairs to bf16 words: W[2*cb+rp] = (key cb*16+g4+2rp lo, +1 hi)
    unsigned W[8];
#pragma unroll
    for (int cb = 0; cb < 4; ++cb) {
      asm("v_cvt_pk_bf16_f32 %0, %1, %2" : "=v"(W[2 * cb + 0]) : "v"(s[cb][0]), "v"(s[cb][1]));
      asm("v_cvt_pk_bf16_f32 %0, %1, %2" : "=v"(W[2 * cb + 1]) : "v"(s[cb][2]), "v"(s[cb][3]));
    }
    // exchange to PV A-fragment: pa[kb] = P[qrow lr][keys kb*32+g*8..+7]
    // dest word (kb,j) <- reg 4kb + 2*(g>>1) + (j&1) of lane ((g&1)*2 + (j>>1))*16 + lr
    union { unsigned u[4]; bf16x8 v; } pa[2];
#pragma unroll
    for (int kb = 0; kb < 2; ++kb)
#pragma unroll
      for (int j = 0; j < 4; ++j) {
        const int sl = ((g & 1) * 2 + (j >> 1)) * 16 + lr;
        const unsigned a = (unsigned)__shfl((int)W[4 * kb + (j & 1)], sl, 64);
        const unsigned b = (unsigned)__shfl((int)W[2 + 4 * kb + (j & 1)], sl, 64);
        pa[kb].u[j] = (g < 2) ? a : b;
      }

    // O += P * V
#pragma unroll
    for (int cb = 0; cb < 4; ++cb)
#pragma unroll
      for (int kb = 0; kb < 2; ++kb)
        O[cb] = __builtin_amdgcn_mfma_f32_16x16x32_bf16(pa[kb].v, vbr[cb][kb], O[cb], 0, 0, 0);

    __builtin_amdgcn_s_barrier();
    cur ^= 1;
  }

  // epilogue: divide by l (redistribute to row g4+r layout), store bf16
  const float linv = 1.0f / lst;
#pragma unroll
  for (int r = 0; r < 4; ++r) {
    const float lr_ = __shfl(linv, (g << 4) + g4 + r, 64);
    const int row = qrow_base + g4 + r;
#pragma unroll
    for (int cb = 0; cb < 4; ++cb)
      aout[(size_t)row * 768 + h * 64 + cb * 16 + lr] = f2bf(O[cb][r] * lr_);
  }
}

// ---------------- launch ----------------
extern "C" void kernel_launch(void* const* d_in, const int* in_sizes, int n_in,
                              void* d_out, int out_size, void* d_ws, size_t ws_size,
                              hipStream_t stream) {
  const float* x = (const float*)d_in[0];
  const float* w_attn = (const float*)d_in[1];
  const float* b_attn = (const float*)d_in[2];
  const float* w_proj = (const float*)d_in[3];
  const float* b_proj = (const float*)d_in[4];
  float* out = (float*)d_out;

  const int S = 4096, D = 768;
  u16* xb = (u16*)d_ws;                 // [4096][768]
  u16* wTa = xb + (size_t)S * D;        // [2304][768]
  u16* wTp = wTa + (size_t)3 * D * D;   // [768][768]
  u16* qkv = wTp + (size_t)D * D;       // [4096][2304]
  u16* abuf = qkv + (size_t)S * 3 * D;  // [4096][768]
  u16* vTb = abuf + (size_t)S * D;      // [12][64][4096]

  cvt_bf16<<<(S * D) / 1024, 256, 0, stream>>>(x, xb, S * D);
  transpose_cvt<<<dim3((3 * D) / 32, D / 32), dim3(32, 8), 0, stream>>>(w_attn, wTa, D, 3 * D);
  transpose_cvt<<<dim3(D / 32, D / 32), dim3(32, 8), 0, stream>>>(w_proj, wTp, D, D);
  gemm_bt<1><<<dim3((3 * D) / 128, S / 128), 256, 0, stream>>>(xb, wTa, b_attn, qkv, S, 3 * D, D);
  vtrans<<<dim3(S / 64, 12), 256, 0, stream>>>(qkv, vTb);
  attn<<<dim3(12 * 64), 256, 0, stream>>>(qkv, vTb, abuf);  // FLAT grid: 768 blocks
  gemm_bt<0><<<dim3(D / 128, S / 128), 256, 0, stream>>>(abuf, wTp, b_proj, out, S, D, D);
}

// Round 6
// 174.450 us; speedup vs baseline: 2.3411x; 1.0060x over previous
//
#include <hip/hip_runtime.h>

typedef __bf16 bf16x8 __attribute__((ext_vector_type(8)));
typedef float f32x4 __attribute__((ext_vector_type(4)));
typedef float f32x16 __attribute__((ext_vector_type(16)));
typedef unsigned short u16;

__device__ inline u16 f2bf(float f) {
  union { float f; unsigned int u; } v; v.f = f;
  unsigned int r = v.u + 0x7fffu + ((v.u >> 16) & 1u);
  return (u16)(r >> 16);
}

__device__ inline void load_lds16(const void* g, void* l) {
  __builtin_amdgcn_global_load_lds((const __attribute__((address_space(1))) unsigned int*)g,
                                   (__attribute__((address_space(3))) unsigned int*)l, 16, 0, 0);
}

// ---------------- prepass: fp32 -> bf16 ----------------
__global__ void cvt_bf16(const float* __restrict__ in, u16* __restrict__ out, int n) {
  int i = (blockIdx.x * blockDim.x + threadIdx.x) * 4;
  if (i < n) {
    float4 v = *(const float4*)(in + i);
    ushort4 o;
    o.x = f2bf(v.x); o.y = f2bf(v.y); o.z = f2bf(v.z); o.w = f2bf(v.w);
    *(ushort4*)(out + i) = o;
  }
}

// in [R][C] fp32 -> out [C][R] bf16
__global__ void transpose_cvt(const float* __restrict__ in, u16* __restrict__ out, int R, int C) {
  __shared__ float tile[32][33];
  int c0 = blockIdx.x * 32, r0 = blockIdx.y * 32;
  int tx = threadIdx.x;
#pragma unroll
  for (int i = threadIdx.y; i < 32; i += 8)
    tile[i][tx] = in[(size_t)(r0 + i) * C + c0 + tx];
  __syncthreads();
#pragma unroll
  for (int i = threadIdx.y; i < 32; i += 8)
    out[(size_t)(c0 + i) * R + r0 + tx] = f2bf(tile[tx][i]);
}

// V transpose: vT[h][d][s] from qkv[s][1536 + h*64 + d]
__global__ __launch_bounds__(256) void vtrans(const u16* __restrict__ qkv, u16* __restrict__ vT) {
  const int h = blockIdx.y;
  const int s0 = blockIdx.x * 64;
  const int tid = threadIdx.x;
  __shared__ u16 T[64][72];
  {
    const int key = tid >> 2, dq = (tid & 3) * 16;
    const u16* g = qkv + (size_t)(s0 + key) * 2304 + 1536 + h * 64 + dq;
    *(uint4*)&T[key][dq] = *(const uint4*)g;
    *(uint4*)&T[key][dq + 8] = *(const uint4*)(g + 8);
  }
  __syncthreads();
  {
    const int d = tid >> 2, sq = (tid & 3) * 16;
    u16 tmp[16];
#pragma unroll
    for (int e = 0; e < 16; ++e) tmp[e] = T[sq + e][d];
    u16* o = vT + ((size_t)h * 64 + d) * 4096 + s0 + sq;
    *(uint4*)o = *(uint4*)tmp;
    *(uint4*)(o + 8) = *(uint4*)(tmp + 8);
  }
}

// ---------------- GEMM: C = A[M,K] * BT[N,K]^T + bias, bf16 in ----------------
template <int BF16_OUT>
__global__ __launch_bounds__(256) void gemm_bt(const u16* __restrict__ A, const u16* __restrict__ BT,
                                               const float* __restrict__ bias, void* __restrict__ Cv,
                                               int M, int N, int K) {
  __shared__ __align__(16) u16 As[128 * 32];
  __shared__ __align__(16) u16 Bs[128 * 32];
  const int tid = threadIdx.x;
  const int wave = tid >> 6, lane = tid & 63;
  const int g = lane >> 4, lr = lane & 15;
  const int m0 = blockIdx.y * 128, n0 = blockIdx.x * 128;
  const int wr = (wave >> 1) * 64, wc = (wave & 1) * 64;
  f32x4 acc[4][4] = {};

  for (int k0 = 0; k0 < K; k0 += 32) {
    __syncthreads();
#pragma unroll
    for (int j = 0; j < 2; ++j) {
      const int e = tid * 8 + j * 2048;
      const int r = e >> 5, c = e & 31;
      const u16* ga = A + (size_t)(m0 + r) * K + k0 + c;
      const u16* gb = BT + (size_t)(n0 + r) * K + k0 + c;
      load_lds16(ga, (void*)(As + wave * 512 + j * 2048));
      load_lds16(gb, (void*)(Bs + wave * 512 + j * 2048));
    }
    __syncthreads();
    const u16* pa = As + (wr + lr) * 32 + g * 8;
    const u16* pb = Bs + (wc + lr) * 32 + g * 8;
    bf16x8 a[4], b[4];
#pragma unroll
    for (int i = 0; i < 4; ++i) a[i] = *(const bf16x8*)(pa + i * 16 * 32);
#pragma unroll
    for (int j = 0; j < 4; ++j) b[j] = *(const bf16x8*)(pb + j * 16 * 32);
#pragma unroll
    for (int i = 0; i < 4; ++i)
#pragma unroll
      for (int j = 0; j < 4; ++j)
        acc[i][j] = __builtin_amdgcn_mfma_f32_16x16x32_bf16(a[i], b[j], acc[i][j], 0, 0, 0);
  }

#pragma unroll
  for (int i = 0; i < 4; ++i)
#pragma unroll
    for (int j = 0; j < 4; ++j)
#pragma unroll
      for (int r = 0; r < 4; ++r) {
        int row = m0 + wr + i * 16 + g * 4 + r;
        int col = n0 + wc + j * 16 + lr;
        float v = acc[i][j][r] + bias[col];
        if (BF16_OUT)
          ((u16*)Cv)[(size_t)row * N + col] = f2bf(v);
        else
          ((float*)Cv)[(size_t)row * N + col] = v;
      }
}

// ---------------- causal flash attention: 1 wave/block, 32x32x16 swapped MFMA ----------------
// qkv: [4096][2304] bf16 (q|k|v), vT: [12][64][4096] bf16. out a: [4096][768] bf16
// Each 64-thread block owns 32 q-rows (lane&31 = q-row), scans 64-key tiles.
// S^T = mfma(K,Q): col=lane&31=qrow -> softmax fully in-lane (+2 shfl_xor(32)).
// O^T = mfma(V^T,P^T): col=qrow -> rescale & epilogue in-lane.
// No barriers. Double-buffered LDS staging via global_load_lds, XOR-swizzled.
__global__ __launch_bounds__(64) void attn(const u16* __restrict__ qkv, const u16* __restrict__ vT,
                                           u16* __restrict__ aout) {
  __shared__ __align__(16) u16 Ks[2][4096];  // [key][dim] swizzled
  __shared__ __align__(16) u16 Vs[2][4096];  // [dim][key] swizzled

  const int bid = blockIdx.x;
  const int h = bid % 12;
  const int qt = 127 - bid / 12;  // heavy q-tiles dispatched first
  const int q0 = qt * 32;

  const int l = threadIdx.x;
  const int lr = l & 31;   // q-row within tile; also A-operand row
  const int H = l >> 5;    // lane half -> k-group
  const int H4 = H * 4, H8 = H * 8;

  const u16* kgb = qkv + 768 + h * 64;
  const u16* vgb = vT + (size_t)h * 64 * 4096;

  // staging map: issue i stages rows 8i..8i+7; lane l -> row 8i+(l>>3), chunk l&7.
  // source chunk = (l&7) ^ swz(row), swz(row) = (row ^ (row>>3)) & 7 = (l>>3) ^ i
  const int srow = l >> 3;
  const int sbase = ((l & 7) ^ srow) << 3;  // ^ (i<<3) applied per issue

  // Q B-fragments: qB[c] = Q[q0+lr][16c + H8 + e], prescaled by 0.125*log2(e)
  bf16x8 qB[4];
  {
    const u16* qp = qkv + (size_t)(q0 + lr) * 2304 + h * 64;
    const float qs = 0.125f * 1.4426950408889634f;
#pragma unroll
    for (int c = 0; c < 4; ++c) {
      bf16x8 raw = *(const bf16x8*)(qp + 16 * c + H8);
#pragma unroll
      for (int e = 0; e < 8; ++e) qB[c][e] = (__bf16)((float)raw[e] * qs);
    }
  }

  f32x16 O[2] = {};
  float mst = -__builtin_inff(), lst = 0.f;

  const int nkt = (q0 + 95) >> 6;  // ceil((q0+32)/64)

  // prologue: stage tile 0 into buffer 0
#pragma unroll
  for (int i = 0; i < 8; ++i) {
    const int sc = sbase ^ (i << 3);
    load_lds16(kgb + (size_t)(8 * i + srow) * 2304 + sc, &Ks[0][i * 512]);
    load_lds16(vgb + (size_t)(8 * i + srow) * 4096 + sc, &Vs[0][i * 512]);
  }

  int cur = 0;
  for (int t = 0; t < nkt; ++t) {
    const int kk0 = t * 64;
    if (t + 1 < nkt) {
      const int kk1 = kk0 + 64;
#pragma unroll
      for (int i = 0; i < 8; ++i) {
        const int sc = sbase ^ (i << 3);
        load_lds16(kgb + (size_t)(kk1 + 8 * i + srow) * 2304 + sc, &Ks[cur ^ 1][i * 512]);
        load_lds16(vgb + (size_t)(8 * i + srow) * 4096 + kk1 + sc, &Vs[cur ^ 1][i * 512]);
      }
      asm volatile("s_waitcnt vmcnt(16)" ::: "memory");
    } else {
      asm volatile("s_waitcnt vmcnt(0)" ::: "memory");
    }
    __builtin_amdgcn_sched_barrier(0);

    // S^T = K * Q^T : s[kb] covers keys 32kb + (r&3)+8*(r>>2)+4H, qrow = lr
    f32x16 s[2] = {};
#pragma unroll
    for (int kb = 0; kb < 2; ++kb) {
      const int row = 32 * kb + lr;
      const int sw = (row ^ (row >> 3)) & 7;
#pragma unroll
      for (int c = 0; c < 4; ++c) {
        bf16x8 kf = *(const bf16x8*)&Ks[cur][row * 64 + (((2 * c + H) ^ sw) << 3)];
        s[kb] = __builtin_amdgcn_mfma_f32_32x32x16_bf16(kf, qB[c], s[kb], 0, 0, 0);
      }
    }

    // V^T A-fragments: vf[da][c] = V^T[32da+lr][16c + H8 + e]
    bf16x8 vf[2][4];
#pragma unroll
    for (int da = 0; da < 2; ++da) {
      const int row = 32 * da + lr;
      const int sw = (row ^ (row >> 3)) & 7;
#pragma unroll
      for (int c = 0; c < 4; ++c)
        vf[da][c] = *(const bf16x8*)&Vs[cur][row * 64 + (((2 * c + H) ^ sw) << 3)];
    }

    // causal mask (last tile only)
    if (t == nkt - 1) {
      const int rel = q0 + lr - kk0;
#pragma unroll
      for (int kb = 0; kb < 2; ++kb)
#pragma unroll
        for (int r = 0; r < 16; ++r)
          if (32 * kb + (r & 3) + 8 * (r >> 2) + H4 > rel) s[kb][r] = -__builtin_inff();
    }

    // in-lane online softmax (log2 domain), defer-max THR=12
    float mx = s[0][0];
#pragma unroll
    for (int kb = 0; kb < 2; ++kb)
#pragma unroll
      for (int r = 0; r < 16; ++r) mx = fmaxf(mx, s[kb][r]);
    mx = fmaxf(mx, __shfl_xor(mx, 32));
    if (__any(mx > mst + 12.f)) {
      const float mn = fmaxf(mst, mx);
      const float alpha = __builtin_amdgcn_exp2f(mst - mn);
      mst = mn;
      lst *= alpha;
      O[0] *= alpha;
      O[1] *= alpha;
    }
    float rs = 0.f;
#pragma unroll
    for (int kb = 0; kb < 2; ++kb)
#pragma unroll
      for (int r = 0; r < 16; ++r) {
        const float p = __builtin_amdgcn_exp2f(s[kb][r] - mst);
        s[kb][r] = p;
        rs += p;
      }
    rs += __shfl_xor(rs, 32);
    lst += rs;

    // pack P to bf16 words: w[8kb+2j2+m] covers keys 32kb+8j2+4H+2m+{0,1}
    unsigned w[16];
#pragma unroll
    for (int kb = 0; kb < 2; ++kb)
#pragma unroll
      for (int j2 = 0; j2 < 4; ++j2) {
        asm("v_cvt_pk_bf16_f32 %0, %1, %2"
            : "=v"(w[kb * 8 + j2 * 2]) : "v"(s[kb][4 * j2]), "v"(s[kb][4 * j2 + 1]));
        asm("v_cvt_pk_bf16_f32 %0, %1, %2"
            : "=v"(w[kb * 8 + j2 * 2 + 1]) : "v"(s[kb][4 * j2 + 2]), "v"(s[kb][4 * j2 + 3]));
      }
    // exchange lane-halves: H=0 needs partner w[4c+m] keys(+4); H=1 needs partner w[4c+2+m]
    unsigned recv[8];
#pragma unroll
    for (int c = 0; c < 4; ++c)
#pragma unroll
      for (int m = 0; m < 2; ++m) {
        const unsigned send = H ? w[4 * c + m] : w[4 * c + 2 + m];
        recv[c * 2 + m] = (unsigned)__shfl_xor((int)send, 32);
      }

    // O^T += V^T * P^T
#pragma unroll
    for (int c = 0; c < 4; ++c) {
      union { unsigned u[4]; bf16x8 v; } Bp;
      Bp.u[0] = H ? recv[2 * c] : w[4 * c];
      Bp.u[1] = H ? recv[2 * c + 1] : w[4 * c + 1];
      Bp.u[2] = H ? w[4 * c + 2] : recv[2 * c];
      Bp.u[3] = H ? w[4 * c + 3] : recv[2 * c + 1];
      O[0] = __builtin_amdgcn_mfma_f32_32x32x16_bf16(vf[0][c], Bp.v, O[0], 0, 0, 0);
      O[1] = __builtin_amdgcn_mfma_f32_32x32x16_bf16(vf[1][c], Bp.v, O[1], 0, 0, 0);
    }

    cur ^= 1;
  }

  // epilogue: O^T reg r of block da = dim (r&3)+8*(r>>2)+4H+32da for q-row q0+lr
  const float inv = 1.0f / lst;
  u16* orow = aout + (size_t)(q0 + lr) * 768 + h * 64;
#pragma unroll
  for (int da = 0; da < 2; ++da)
#pragma unroll
    for (int j2 = 0; j2 < 4; ++j2) {
      ushort4 st;
      st.x = f2bf(O[da][4 * j2 + 0] * inv);
      st.y = f2bf(O[da][4 * j2 + 1] * inv);
      st.z = f2bf(O[da][4 * j2 + 2] * inv);
      st.w = f2bf(O[da][4 * j2 + 3] * inv);
      *(ushort4*)(orow + 32 * da + 8 * j2 + H4) = st;
    }
}

// ---------------- launch ----------------
extern "C" void kernel_launch(void* const* d_in, const int* in_sizes, int n_in,
                              void* d_out, int out_size, void* d_ws, size_t ws_size,
                              hipStream_t stream) {
  const float* x = (const float*)d_in[0];
  const float* w_attn = (const float*)d_in[1];
  const float* b_attn = (const float*)d_in[2];
  const float* w_proj = (const float*)d_in[3];
  const float* b_proj = (const float*)d_in[4];
  float* out = (float*)d_out;

  const int S = 4096, D = 768;
  u16* xb = (u16*)d_ws;                 // [4096][768]
  u16* wTa = xb + (size_t)S * D;        // [2304][768]
  u16* wTp = wTa + (size_t)3 * D * D;   // [768][768]
  u16* qkv = wTp + (size_t)D * D;       // [4096][2304]
  u16* abuf = qkv + (size_t)S * 3 * D;  // [4096][768]
  u16* vTb = abuf + (size_t)S * D;      // [12][64][4096]

  cvt_bf16<<<(S * D) / 1024, 256, 0, stream>>>(x, xb, S * D);
  transpose_cvt<<<dim3((3 * D) / 32, D / 32), dim3(32, 8), 0, stream>>>(w_attn, wTa, D, 3 * D);
  transpose_cvt<<<dim3(D / 32, D / 32), dim3(32, 8), 0, stream>>>(w_proj, wTp, D, D);
  gemm_bt<1><<<dim3((3 * D) / 128, S / 128), 256, 0, stream>>>(xb, wTa, b_attn, qkv, S, 3 * D, D);
  vtrans<<<dim3(S / 64, 12), 256, 0, stream>>>(qkv, vTb);
  attn<<<dim3(12 * 128), 64, 0, stream>>>(qkv, vTb, abuf);
  gemm_bt<0><<<dim3(D / 128, S / 128), 256, 0, stream>>>(abuf, wTp, b_proj, out, S, D, D);
}

// Round 7
// 167.661 us; speedup vs baseline: 2.4359x; 1.0405x over previous
//
#include <hip/hip_runtime.h>

typedef __bf16 bf16x8 __attribute__((ext_vector_type(8)));
typedef float f32x4 __attribute__((ext_vector_type(4)));
typedef float f32x16 __attribute__((ext_vector_type(16)));
typedef unsigned short u16;

__device__ inline u16 f2bf(float f) {
  union { float f; unsigned int u; } v; v.f = f;
  unsigned int r = v.u + 0x7fffu + ((v.u >> 16) & 1u);
  return (u16)(r >> 16);
}

__device__ inline void load_lds16(const void* g, void* l) {
  __builtin_amdgcn_global_load_lds((const __attribute__((address_space(1))) unsigned int*)g,
                                   (__attribute__((address_space(3))) unsigned int*)l, 16, 0, 0);
}

// ---------------- prepass: fp32 -> bf16 ----------------
__global__ void cvt_bf16(const float* __restrict__ in, u16* __restrict__ out, int n) {
  int i = (blockIdx.x * blockDim.x + threadIdx.x) * 4;
  if (i < n) {
    float4 v = *(const float4*)(in + i);
    ushort4 o;
    o.x = f2bf(v.x); o.y = f2bf(v.y); o.z = f2bf(v.z); o.w = f2bf(v.w);
    *(ushort4*)(out + i) = o;
  }
}

// in [R][C] fp32 -> out [C][R] bf16
__global__ void transpose_cvt(const float* __restrict__ in, u16* __restrict__ out, int R, int C) {
  __shared__ float tile[32][33];
  int c0 = blockIdx.x * 32, r0 = blockIdx.y * 32;
  int tx = threadIdx.x;
#pragma unroll
  for (int i = threadIdx.y; i < 32; i += 8)
    tile[i][tx] = in[(size_t)(r0 + i) * C + c0 + tx];
  __syncthreads();
#pragma unroll
  for (int i = threadIdx.y; i < 32; i += 8)
    out[(size_t)(c0 + i) * R + r0 + tx] = f2bf(tile[tx][i]);
}

// V transpose: vT[h][d][s] from qkv[s][1536 + h*64 + d]
__global__ __launch_bounds__(256) void vtrans(const u16* __restrict__ qkv, u16* __restrict__ vT) {
  const int h = blockIdx.y;
  const int s0 = blockIdx.x * 64;
  const int tid = threadIdx.x;
  __shared__ u16 T[64][72];
  {
    const int key = tid >> 2, dq = (tid & 3) * 16;
    const u16* g = qkv + (size_t)(s0 + key) * 2304 + 1536 + h * 64 + dq;
    *(uint4*)&T[key][dq] = *(const uint4*)g;
    *(uint4*)&T[key][dq + 8] = *(const uint4*)(g + 8);
  }
  __syncthreads();
  {
    const int d = tid >> 2, sq = (tid & 3) * 16;
    u16 tmp[16];
#pragma unroll
    for (int e = 0; e < 16; ++e) tmp[e] = T[sq + e][d];
    u16* o = vT + ((size_t)h * 64 + d) * 4096 + s0 + sq;
    *(uint4*)o = *(uint4*)tmp;
    *(uint4*)(o + 8) = *(uint4*)(tmp + 8);
  }
}

// ---------------- GEMM: C = A[M,K] * BT[N,K]^T + bias, bf16 in ----------------
template <int BF16_OUT>
__global__ __launch_bounds__(256) void gemm_bt(const u16* __restrict__ A, const u16* __restrict__ BT,
                                               const float* __restrict__ bias, void* __restrict__ Cv,
                                               int M, int N, int K) {
  __shared__ __align__(16) u16 As[128 * 32];
  __shared__ __align__(16) u16 Bs[128 * 32];
  const int tid = threadIdx.x;
  const int wave = tid >> 6, lane = tid & 63;
  const int g = lane >> 4, lr = lane & 15;
  const int m0 = blockIdx.y * 128, n0 = blockIdx.x * 128;
  const int wr = (wave >> 1) * 64, wc = (wave & 1) * 64;
  f32x4 acc[4][4] = {};

  for (int k0 = 0; k0 < K; k0 += 32) {
    __syncthreads();
#pragma unroll
    for (int j = 0; j < 2; ++j) {
      const int e = tid * 8 + j * 2048;
      const int r = e >> 5, c = e & 31;
      const u16* ga = A + (size_t)(m0 + r) * K + k0 + c;
      const u16* gb = BT + (size_t)(n0 + r) * K + k0 + c;
      load_lds16(ga, (void*)(As + wave * 512 + j * 2048));
      load_lds16(gb, (void*)(Bs + wave * 512 + j * 2048));
    }
    __syncthreads();
    const u16* pa = As + (wr + lr) * 32 + g * 8;
    const u16* pb = Bs + (wc + lr) * 32 + g * 8;
    bf16x8 a[4], b[4];
#pragma unroll
    for (int i = 0; i < 4; ++i) a[i] = *(const bf16x8*)(pa + i * 16 * 32);
#pragma unroll
    for (int j = 0; j < 4; ++j) b[j] = *(const bf16x8*)(pb + j * 16 * 32);
#pragma unroll
    for (int i = 0; i < 4; ++i)
#pragma unroll
      for (int j = 0; j < 4; ++j)
        acc[i][j] = __builtin_amdgcn_mfma_f32_16x16x32_bf16(a[i], b[j], acc[i][j], 0, 0, 0);
  }

#pragma unroll
  for (int i = 0; i < 4; ++i)
#pragma unroll
    for (int j = 0; j < 4; ++j)
#pragma unroll
      for (int r = 0; r < 4; ++r) {
        int row = m0 + wr + i * 16 + g * 4 + r;
        int col = n0 + wc + j * 16 + lr;
        float v = acc[i][j][r] + bias[col];
        if (BF16_OUT)
          ((u16*)Cv)[(size_t)row * N + col] = f2bf(v);
        else
          ((float*)Cv)[(size_t)row * N + col] = v;
      }
}

// ---------------- causal flash attention: 1 wave/block, split-K, 32x32x16 swapped MFMA ----------------
// Each 64-thread block processes chunk c (<= CH 64-key tiles) of q-tile qt, head h.
// S^T = mfma(K,Q): col=lane&31=qrow -> softmax fully in-lane. O^T = mfma(V^T,P^T).
// Partials (unnormalized O^T bf16, m/l fp32) go to scratch; combine kernel merges.
template <int CH, int DIRECT>
__global__ __launch_bounds__(64) void attn(const u16* __restrict__ qkv, const u16* __restrict__ vT,
                                           u16* __restrict__ pO, float* __restrict__ pml,
                                           u16* __restrict__ aout) {
  __shared__ __align__(16) u16 KV[4][4096];  // K buf0,buf1, V buf0,buf1 (swizzled 64x64)

  const int bid = blockIdx.x;
  const int h = bid % 12;
  int qt, c;
  if (CH == 64) {
    qt = 127 - bid / 12;
    c = 0;
  } else {
    const int u = 319 - bid / 12;  // heavy chunks first
    if (u < 32) { qt = u; c = 0; }
    else if (u < 96) { qt = 32 + ((u - 32) >> 1); c = (u - 32) & 1; }
    else if (u < 192) { qt = 64 + (u - 96) / 3; c = (u - 96) % 3; }
    else { qt = 96 + ((u - 192) >> 2); c = (u - 192) & 3; }
  }
  const int q0 = qt * 32;
  const int nkt = (qt >> 1) + 1;
  const int t0 = c * CH;
  const int tend = min(nkt, t0 + CH);

  const int l = threadIdx.x;
  const int lr = l & 31;   // q-row within tile
  const int H = l >> 5;    // lane half
  const int H4 = H * 4, H8 = H * 8;

  const u16* kgb = qkv + 768 + h * 64;
  const u16* vgb = vT + (size_t)h * 64 * 4096;

  // per-lane staging offsets (hoisted; per-tile part is wave-uniform -> SGPR)
  const int srow = l >> 3;
  const int sbase = ((l & 7) ^ srow) << 3;
  int kSo[8], vSo[8];
#pragma unroll
  for (int i = 0; i < 8; ++i) {
    const int sc = sbase ^ (i << 3);
    kSo[i] = (8 * i + srow) * 2304 + sc;
    vSo[i] = (8 * i + srow) * 4096 + sc;
  }

  // hoisted LDS read pointers (into buf0 of K; V = +8192 elems, buf1 = +4096 elems)
  const u16* Rd[2][4];
#pragma unroll
  for (int b2 = 0; b2 < 2; ++b2) {
    const int row = 32 * b2 + lr;
    const int sw = (row ^ (row >> 3)) & 7;
#pragma unroll
    for (int cc = 0; cc < 4; ++cc)
      Rd[b2][cc] = &KV[0][row * 64 + (((2 * cc + H) ^ sw) << 3)];
  }

  // Q B-fragments, prescaled by 0.125*log2(e)
  bf16x8 qB[4];
  {
    const u16* qp = qkv + (size_t)(q0 + lr) * 2304 + h * 64;
    const float qs = 0.125f * 1.4426950408889634f;
#pragma unroll
    for (int cc = 0; cc < 4; ++cc) {
      bf16x8 raw = *(const bf16x8*)(qp + 16 * cc + H8);
#pragma unroll
      for (int e = 0; e < 8; ++e) qB[cc][e] = (__bf16)((float)raw[e] * qs);
    }
  }

  f32x16 O[2] = {};
  float mst = -__builtin_inff(), lst = 0.f;

#define STAGE(T, BUF)                                                      \
  {                                                                        \
    const size_t kk = (size_t)(T) * 64;                                    \
    _Pragma("unroll") for (int i = 0; i < 8; ++i) {                        \
      load_lds16(kgb + kk * 2304 + kSo[i], &KV[(BUF)][i * 512]);           \
      load_lds16(vgb + kk + vSo[i], &KV[2 + (BUF)][i * 512]);              \
    }                                                                      \
  }

#define BODY(T, BUF)                                                                        \
  {                                                                                         \
    if ((T) + 1 < tend) {                                                                   \
      STAGE((T) + 1, (BUF) ^ 1);                                                            \
      asm volatile("s_waitcnt vmcnt(16)" ::: "memory");                                     \
    } else {                                                                                \
      asm volatile("s_waitcnt vmcnt(0)" ::: "memory");                                      \
    }                                                                                       \
    __builtin_amdgcn_sched_barrier(0);                                                      \
    f32x16 s[2] = {};                                                                       \
    _Pragma("unroll") for (int kb = 0; kb < 2; ++kb)                                        \
      _Pragma("unroll") for (int cc = 0; cc < 4; ++cc) {                                    \
        bf16x8 kf = *(const bf16x8*)(Rd[kb][cc] + (BUF) * 4096);                            \
        s[kb] = __builtin_amdgcn_mfma_f32_32x32x16_bf16(kf, qB[cc], s[kb], 0, 0, 0);        \
      }                                                                                     \
    bf16x8 vf[2][4];                                                                        \
    _Pragma("unroll") for (int da = 0; da < 2; ++da)                                        \
      _Pragma("unroll") for (int cc = 0; cc < 4; ++cc)                                      \
        vf[da][cc] = *(const bf16x8*)(Rd[da][cc] + 8192 + (BUF) * 4096);                    \
    if ((T) == nkt - 1) {                                                                   \
      const int rel = q0 + lr - (T) * 64;                                                   \
      _Pragma("unroll") for (int kb = 0; kb < 2; ++kb)                                      \
        _Pragma("unroll") for (int r = 0; r < 16; ++r)                                      \
          if (32 * kb + (r & 3) + 8 * (r >> 2) + H4 > rel) s[kb][r] = -__builtin_inff();    \
    }                                                                                       \
    float mx = s[0][0];                                                                     \
    _Pragma("unroll") for (int kb = 0; kb < 2; ++kb)                                        \
      _Pragma("unroll") for (int r = 0; r < 16; ++r) mx = fmaxf(mx, s[kb][r]);              \
    mx = fmaxf(mx, __shfl_xor(mx, 32));                                                     \
    if (__any(mx > mst + 12.f)) {                                                           \
      const float mn = fmaxf(mst, mx);                                                      \
      const float alpha = __builtin_amdgcn_exp2f(mst - mn);                                 \
      mst = mn;                                                                             \
      lst *= alpha;                                                                         \
      O[0] *= alpha;                                                                        \
      O[1] *= alpha;                                                                        \
    }                                                                                       \
    float rs = 0.f;                                                                         \
    _Pragma("unroll") for (int kb = 0; kb < 2; ++kb)                                        \
      _Pragma("unroll") for (int r = 0; r < 16; ++r) {                                      \
        const float p = __builtin_amdgcn_exp2f(s[kb][r] - mst);                             \
        s[kb][r] = p;                                                                       \
        rs += p;                                                                            \
      }                                                                                     \
    rs += __shfl_xor(rs, 32);                                                               \
    lst += rs;                                                                              \
    unsigned w[16];                                                                         \
    _Pragma("unroll") for (int kb = 0; kb < 2; ++kb)                                        \
      _Pragma("unroll") for (int j2 = 0; j2 < 4; ++j2) {                                    \
        asm("v_cvt_pk_bf16_f32 %0, %1, %2"                                                  \
            : "=v"(w[kb * 8 + j2 * 2]) : "v"(s[kb][4 * j2]), "v"(s[kb][4 * j2 + 1]));       \
        asm("v_cvt_pk_bf16_f32 %0, %1, %2"                                                  \
            : "=v"(w[kb * 8 + j2 * 2 + 1]) : "v"(s[kb][4 * j2 + 2]), "v"(s[kb][4 * j2 + 3])); \
      }                                                                                     \
    unsigned recv[8];                                                                       \
    _Pragma("unroll") for (int cc = 0; cc < 4; ++cc)                                        \
      _Pragma("unroll") for (int m = 0; m < 2; ++m) {                                       \
        const unsigned send = H ? w[4 * cc + m] : w[4 * cc + 2 + m];                        \
        recv[cc * 2 + m] = (unsigned)__shfl_xor((int)send, 32);                             \
      }                                                                                     \
    _Pragma("unroll") for (int cc = 0; cc < 4; ++cc) {                                      \
      union { unsigned u[4]; bf16x8 v; } Bp;                                                \
      Bp.u[0] = H ? recv[2 * cc] : w[4 * cc];                                               \
      Bp.u[1] = H ? recv[2 * cc + 1] : w[4 * cc + 1];                                       \
      Bp.u[2] = H ? w[4 * cc + 2] : recv[2 * cc];                                           \
      Bp.u[3] = H ? w[4 * cc + 3] : recv[2 * cc + 1];                                       \
      O[0] = __builtin_amdgcn_mfma_f32_32x32x16_bf16(vf[0][cc], Bp.v, O[0], 0, 0, 0);       \
      O[1] = __builtin_amdgcn_mfma_f32_32x32x16_bf16(vf[1][cc], Bp.v, O[1], 0, 0, 0);       \
    }                                                                                       \
  }

  STAGE(t0, 0);
  int t = t0;
  for (; t + 2 <= tend; t += 2) {
    BODY(t, 0);
    BODY(t + 1, 1);
  }
  if (t < tend) BODY(t, 0);
#undef BODY
#undef STAGE

  if (DIRECT) {
    const float inv = 1.0f / lst;
    u16* orow = aout + (size_t)(q0 + lr) * 768 + h * 64;
#pragma unroll
    for (int da = 0; da < 2; ++da)
#pragma unroll
      for (int j2 = 0; j2 < 4; ++j2) {
        ushort4 st;
        st.x = f2bf(O[da][4 * j2 + 0] * inv);
        st.y = f2bf(O[da][4 * j2 + 1] * inv);
        st.z = f2bf(O[da][4 * j2 + 2] * inv);
        st.w = f2bf(O[da][4 * j2 + 3] * inv);
        *(ushort4*)(orow + 32 * da + 8 * j2 + H4) = st;
      }
  } else {
    const int ncmax = (CH == 16) ? 4 : 1;
    const int slot = (h * 128 + qt) * ncmax + c;
    u16* po = pO + (size_t)slot * 2048 + lr * 64;
#pragma unroll
    for (int da = 0; da < 2; ++da)
#pragma unroll
      for (int j2 = 0; j2 < 4; ++j2) {
        ushort4 st;
        st.x = f2bf(O[da][4 * j2 + 0]);
        st.y = f2bf(O[da][4 * j2 + 1]);
        st.z = f2bf(O[da][4 * j2 + 2]);
        st.w = f2bf(O[da][4 * j2 + 3]);
        *(ushort4*)(po + 32 * da + 8 * j2 + H4) = st;
      }
    if (H == 0) {
      float2 ml; ml.x = mst; ml.y = lst;
      *(float2*)(pml + (size_t)slot * 64 + lr * 2) = ml;
    }
  }
}

// combine partials: one block per (h, qt); thread = (row 0..31) x (dim-half 0..1)
__global__ __launch_bounds__(64) void combine(const u16* __restrict__ pO, const float* __restrict__ pml,
                                              u16* __restrict__ aout, int ncmax, int CHv) {
  const int bid = blockIdx.x;
  const int h = bid % 12, qt = bid / 12;
  const int nkt = (qt >> 1) + 1;
  const int nc = (nkt + CHv - 1) / CHv;
  const int sb = (h * 128 + qt) * ncmax;
  const int t = threadIdx.x;
  const int row = t & 31, H = t >> 5;

  float m[4], lw[4];
  float M = -__builtin_inff();
#pragma unroll
  for (int c = 0; c < 4; ++c)
    if (c < nc) {
      m[c] = pml[(size_t)(sb + c) * 64 + row * 2];
      M = fmaxf(M, m[c]);
    }
  float L = 0.f;
#pragma unroll
  for (int c = 0; c < 4; ++c)
    if (c < nc) {
      lw[c] = __builtin_amdgcn_exp2f(m[c] - M);
      L += pml[(size_t)(sb + c) * 64 + row * 2 + 1] * lw[c];
    }

  float acc[32] = {};
#pragma unroll
  for (int c = 0; c < 4; ++c)
    if (c < nc) {
      const u16* p = pO + (size_t)(sb + c) * 2048 + row * 64 + 32 * H;
      const float wgt = lw[c];
#pragma unroll
      for (int k = 0; k < 4; ++k) {
        bf16x8 v = *(const bf16x8*)(p + 8 * k);
#pragma unroll
        for (int e = 0; e < 8; ++e) acc[k * 8 + e] += (float)v[e] * wgt;
      }
    }

  const float inv = 1.0f / L;
  u16 ov[32];
#pragma unroll
  for (int d = 0; d < 32; ++d) ov[d] = f2bf(acc[d] * inv);
  u16* dst = aout + (size_t)(qt * 32 + row) * 768 + h * 64 + 32 * H;
#pragma unroll
  for (int k = 0; k < 4; ++k) *(uint4*)(dst + 8 * k) = *(const uint4*)(ov + 8 * k);
}

// ---------------- launch ----------------
extern "C" void kernel_launch(void* const* d_in, const int* in_sizes, int n_in,
                              void* d_out, int out_size, void* d_ws, size_t ws_size,
                              hipStream_t stream) {
  const float* x = (const float*)d_in[0];
  const float* w_attn = (const float*)d_in[1];
  const float* b_attn = (const float*)d_in[2];
  const float* w_proj = (const float*)d_in[3];
  const float* b_proj = (const float*)d_in[4];
  float* out = (float*)d_out;

  const int S = 4096, D = 768;
  u16* xb = (u16*)d_ws;                 // [4096][768]
  u16* wTa = xb + (size_t)S * D;        // [2304][768]
  u16* wTp = wTa + (size_t)3 * D * D;   // [768][768]
  u16* qkv = wTp + (size_t)D * D;       // [4096][2304]
  u16* abuf = qkv + (size_t)S * 3 * D;  // [4096][768]
  u16* vTb = abuf + (size_t)S * D;      // [12][64][4096]
  u16* pO = vTb + (size_t)12 * 64 * 4096;

  const size_t base_bytes = (size_t)(3145728 + 1769472 + 589824 + 9437184 + 3145728 + 3145728) * 2;
  const size_t need16 = base_bytes + (size_t)6144 * 2048 * 2 + (size_t)6144 * 64 * 4;
  const size_t need64 = base_bytes + (size_t)1536 * 2048 * 2 + (size_t)1536 * 64 * 4;

  cvt_bf16<<<(S * D) / 1024, 256, 0, stream>>>(x, xb, S * D);
  transpose_cvt<<<dim3((3 * D) / 32, D / 32), dim3(32, 8), 0, stream>>>(w_attn, wTa, D, 3 * D);
  transpose_cvt<<<dim3(D / 32, D / 32), dim3(32, 8), 0, stream>>>(w_proj, wTp, D, D);
  gemm_bt<1><<<dim3((3 * D) / 128, S / 128), 256, 0, stream>>>(xb, wTa, b_attn, qkv, S, 3 * D, D);
  vtrans<<<dim3(S / 64, 12), 256, 0, stream>>>(qkv, vTb);

  if (ws_size >= need16) {
    float* pml = (float*)(pO + (size_t)6144 * 2048);
    attn<16, 0><<<dim3(12 * 320), 64, 0, stream>>>(qkv, vTb, pO, pml, abuf);
    combine<<<dim3(12 * 128), 64, 0, stream>>>(pO, pml, abuf, 4, 16);
  } else if (ws_size >= need64) {
    float* pml = (float*)(pO + (size_t)1536 * 2048);
    attn<64, 0><<<dim3(12 * 128), 64, 0, stream>>>(qkv, vTb, pO, pml, abuf);
    combine<<<dim3(12 * 128), 64, 0, stream>>>(pO, pml, abuf, 1, 64);
  } else {
    attn<64, 1><<<dim3(12 * 128), 64, 0, stream>>>(qkv, vTb, abuf, (float*)abuf, abuf);
  }

  gemm_bt<0><<<dim3(D / 128, S / 128), 256, 0, stream>>>(abuf, wTp, b_proj, out, S, D, D);
}

// Round 8
// 143.395 us; speedup vs baseline: 2.8481x; 1.1692x over previous
//
#include <hip/hip_runtime.h>

typedef __bf16 bf16x8 __attribute__((ext_vector_type(8)));
typedef float f32x4 __attribute__((ext_vector_type(4)));
typedef float f32x16 __attribute__((ext_vector_type(16)));
typedef unsigned short u16;

__device__ inline u16 f2bf(float f) {
  union { float f; unsigned int u; } v; v.f = f;
  unsigned int r = v.u + 0x7fffu + ((v.u >> 16) & 1u);
  return (u16)(r >> 16);
}

__device__ inline void load_lds16(const void* g, void* l) {
  __builtin_amdgcn_global_load_lds((const __attribute__((address_space(1))) unsigned int*)g,
                                   (__attribute__((address_space(3))) unsigned int*)l, 16, 0, 0);
}

// ---------------- prepass: fp32 -> bf16 ----------------
__global__ void cvt_bf16(const float* __restrict__ in, u16* __restrict__ out, int n) {
  int i = (blockIdx.x * blockDim.x + threadIdx.x) * 4;
  if (i < n) {
    float4 v = *(const float4*)(in + i);
    ushort4 o;
    o.x = f2bf(v.x); o.y = f2bf(v.y); o.z = f2bf(v.z); o.w = f2bf(v.w);
    *(ushort4*)(out + i) = o;
  }
}

// in [R][C] fp32 -> out [C][R] bf16
__global__ void transpose_cvt(const float* __restrict__ in, u16* __restrict__ out, int R, int C) {
  __shared__ float tile[32][33];
  int c0 = blockIdx.x * 32, r0 = blockIdx.y * 32;
  int tx = threadIdx.x;
#pragma unroll
  for (int i = threadIdx.y; i < 32; i += 8)
    tile[i][tx] = in[(size_t)(r0 + i) * C + c0 + tx];
  __syncthreads();
#pragma unroll
  for (int i = threadIdx.y; i < 32; i += 8)
    out[(size_t)(c0 + i) * R + r0 + tx] = f2bf(tile[tx][i]);
}

// V transpose: vT[h][d][s] from qkv[s][1536 + h*64 + d]
__global__ __launch_bounds__(256) void vtrans(const u16* __restrict__ qkv, u16* __restrict__ vT) {
  const int h = blockIdx.y;
  const int s0 = blockIdx.x * 64;
  const int tid = threadIdx.x;
  __shared__ u16 T[64][72];
  {
    const int key = tid >> 2, dq = (tid & 3) * 16;
    const u16* g = qkv + (size_t)(s0 + key) * 2304 + 1536 + h * 64 + dq;
    *(uint4*)&T[key][dq] = *(const uint4*)g;
    *(uint4*)&T[key][dq + 8] = *(const uint4*)(g + 8);
  }
  __syncthreads();
  {
    const int d = tid >> 2, sq = (tid & 3) * 16;
    u16 tmp[16];
#pragma unroll
    for (int e = 0; e < 16; ++e) tmp[e] = T[sq + e][d];
    u16* o = vT + ((size_t)h * 64 + d) * 4096 + s0 + sq;
    *(uint4*)o = *(uint4*)tmp;
    *(uint4*)(o + 8) = *(uint4*)(tmp + 8);
  }
}

// ---------------- GEMM: C = A[M,K] * BT[N,K]^T + bias, bf16 in ----------------
template <int BF16_OUT>
__global__ __launch_bounds__(256) void gemm_bt(const u16* __restrict__ A, const u16* __restrict__ BT,
                                               const float* __restrict__ bias, void* __restrict__ Cv,
                                               int M, int N, int K) {
  __shared__ __align__(16) u16 As[128 * 32];
  __shared__ __align__(16) u16 Bs[128 * 32];
  const int tid = threadIdx.x;
  const int wave = tid >> 6, lane = tid & 63;
  const int g = lane >> 4, lr = lane & 15;
  const int m0 = blockIdx.y * 128, n0 = blockIdx.x * 128;
  const int wr = (wave >> 1) * 64, wc = (wave & 1) * 64;
  f32x4 acc[4][4] = {};

  for (int k0 = 0; k0 < K; k0 += 32) {
    __syncthreads();
#pragma unroll
    for (int j = 0; j < 2; ++j) {
      const int e = tid * 8 + j * 2048;
      const int r = e >> 5, c = e & 31;
      const u16* ga = A + (size_t)(m0 + r) * K + k0 + c;
      const u16* gb = BT + (size_t)(n0 + r) * K + k0 + c;
      load_lds16(ga, (void*)(As + wave * 512 + j * 2048));
      load_lds16(gb, (void*)(Bs + wave * 512 + j * 2048));
    }
    __syncthreads();
    const u16* pa = As + (wr + lr) * 32 + g * 8;
    const u16* pb = Bs + (wc + lr) * 32 + g * 8;
    bf16x8 a[4], b[4];
#pragma unroll
    for (int i = 0; i < 4; ++i) a[i] = *(const bf16x8*)(pa + i * 16 * 32);
#pragma unroll
    for (int j = 0; j < 4; ++j) b[j] = *(const bf16x8*)(pb + j * 16 * 32);
#pragma unroll
    for (int i = 0; i < 4; ++i)
#pragma unroll
      for (int j = 0; j < 4; ++j)
        acc[i][j] = __builtin_amdgcn_mfma_f32_16x16x32_bf16(a[i], b[j], acc[i][j], 0, 0, 0);
  }

#pragma unroll
  for (int i = 0; i < 4; ++i)
#pragma unroll
    for (int j = 0; j < 4; ++j)
#pragma unroll
      for (int r = 0; r < 4; ++r) {
        int row = m0 + wr + i * 16 + g * 4 + r;
        int col = n0 + wc + j * 16 + lr;
        float v = acc[i][j][r] + bias[col];
        if (BF16_OUT)
          ((u16*)Cv)[(size_t)row * N + col] = f2bf(v);
        else
          ((float*)Cv)[(size_t)row * N + col] = v;
      }
}

// ---------------- causal flash attention: 4 waves/block share staged K/V ----------------
// Block = (head h, q-tile group g of 4, key-chunk c). Wave w owns q-tile qt = 4g+w (32 rows).
// All waves consume the SAME staged 64-key tiles (4-way LDS reuse). Split-K partials to
// scratch (bf16 O^T + fp32 m/l); combine merges. Fully-masked tiles use the finite -30000
// sentinel so non-participating waves emit exactly-zero-weighted partials.
#define MNEG 30000.0f
template <int CH, int DIRECT>
__global__ __launch_bounds__(256, 3) void attn(const u16* __restrict__ qkv, const u16* __restrict__ vT,
                                               u16* __restrict__ pO, float* __restrict__ pml,
                                               u16* __restrict__ aout) {
  __shared__ __align__(16) u16 KV[4][4096];  // K buf0,buf1, V buf0,buf1 (swizzled 64x64)

  const int bid = blockIdx.x;
  const int h = bid % 12;
  int g, c;
  if (DIRECT) {
    g = 31 - bid / 12;
    c = 0;
  } else {
    const int u = 79 - bid / 12;  // heavy chunks first
    if (u < 8) { g = u; c = 0; }
    else if (u < 24) { g = 8 + ((u - 8) >> 1); c = (u - 8) & 1; }
    else if (u < 48) { g = 16 + (u - 24) / 3; c = (u - 24) % 3; }
    else { g = 24 + ((u - 48) >> 2); c = (u - 48) & 3; }
  }

  const int tid = threadIdx.x;
  const int wave = tid >> 6;
  const int l = tid & 63;
  const int lr = l & 31;   // q-row within wave's tile
  const int H = l >> 5;    // lane half
  const int H4 = H * 4, H8 = H * 8;

  const int qt = 4 * g + wave;
  const int q0 = qt * 32;
  const int nkt = (qt >> 1) + 1;              // tiles this wave needs
  const int t0 = DIRECT ? 0 : c * CH;
  const int tend = min(2 * g + 2, t0 + CH);   // block-uniform tile range

  const u16* kgb = qkv + 768 + h * 64;
  const u16* vgb = vT + (size_t)h * 64 * 4096;

  // staging: wave w issue i covers rows 16w+8i..+7; lane -> row 16w+8i+srow, chunk l&7
  const int srow = l >> 3;
  int kSo[2], vSo[2];
#pragma unroll
  for (int i = 0; i < 2; ++i) {
    const int row = 16 * wave + 8 * i + srow;
    const int sc = ((l & 7) ^ srow ^ (2 * wave + i)) << 3;
    kSo[i] = row * 2304 + sc;
    vSo[i] = row * 4096 + sc;
  }

  // hoisted LDS read pointers (K buf0; V = +8192, buf1 = +4096)
  const u16* Rd[2][4];
#pragma unroll
  for (int b2 = 0; b2 < 2; ++b2) {
    const int row = 32 * b2 + lr;
    const int sw = (row ^ (row >> 3)) & 7;
#pragma unroll
    for (int cc = 0; cc < 4; ++cc)
      Rd[b2][cc] = &KV[0][row * 64 + (((2 * cc + H) ^ sw) << 3)];
  }

  // Q B-fragments, prescaled by 0.125*log2(e)
  bf16x8 qB[4];
  {
    const u16* qp = qkv + (size_t)(q0 + lr) * 2304 + h * 64;
    const float qs = 0.125f * 1.4426950408889634f;
#pragma unroll
    for (int cc = 0; cc < 4; ++cc) {
      bf16x8 raw = *(const bf16x8*)(qp + 16 * cc + H8);
#pragma unroll
      for (int e = 0; e < 8; ++e) qB[cc][e] = (__bf16)((float)raw[e] * qs);
    }
  }

  f32x16 O[2] = {};
  float mst = -MNEG, lst = 0.f;

#define STAGE(T, BUF)                                                      \
  {                                                                        \
    const size_t kk = (size_t)(T) * 64;                                    \
    _Pragma("unroll") for (int i = 0; i < 2; ++i) {                        \
      load_lds16(kgb + kk * 2304 + kSo[i], &KV[(BUF)][(2 * wave + i) * 512]); \
      load_lds16(vgb + kk + vSo[i], &KV[2 + (BUF)][(2 * wave + i) * 512]); \
    }                                                                      \
  }

#define BODY(T, BUF)                                                                        \
  {                                                                                         \
    if ((T) + 1 < tend) {                                                                   \
      STAGE((T) + 1, (BUF) ^ 1);                                                            \
      asm volatile("s_waitcnt vmcnt(4)" ::: "memory");                                      \
    } else {                                                                                \
      asm volatile("s_waitcnt vmcnt(0)" ::: "memory");                                      \
    }                                                                                       \
    __builtin_amdgcn_s_barrier();                                                           \
    __builtin_amdgcn_sched_barrier(0);                                                      \
    f32x16 s[2] = {};                                                                       \
    _Pragma("unroll") for (int kb = 0; kb < 2; ++kb)                                        \
      _Pragma("unroll") for (int cc = 0; cc < 4; ++cc) {                                    \
        bf16x8 kf = *(const bf16x8*)(Rd[kb][cc] + (BUF) * 4096);                            \
        s[kb] = __builtin_amdgcn_mfma_f32_32x32x16_bf16(kf, qB[cc], s[kb], 0, 0, 0);        \
      }                                                                                     \
    bf16x8 vf[2][4];                                                                        \
    _Pragma("unroll") for (int da = 0; da < 2; ++da)                                        \
      _Pragma("unroll") for (int cc = 0; cc < 4; ++cc)                                      \
        vf[da][cc] = *(const bf16x8*)(Rd[da][cc] + 8192 + (BUF) * 4096);                    \
    if ((T) >= nkt - 1) {                                                                   \
      const int rel = q0 + lr - (T) * 64;                                                   \
      _Pragma("unroll") for (int kb = 0; kb < 2; ++kb)                                      \
        _Pragma("unroll") for (int r = 0; r < 16; ++r)                                      \
          if (32 * kb + (r & 3) + 8 * (r >> 2) + H4 > rel) s[kb][r] = -MNEG;                \
    }                                                                                       \
    float mx = s[0][0];                                                                     \
    _Pragma("unroll") for (int kb = 0; kb < 2; ++kb)                                        \
      _Pragma("unroll") for (int r = 0; r < 16; ++r) mx = fmaxf(mx, s[kb][r]);              \
    mx = fmaxf(mx, __shfl_xor(mx, 32));                                                     \
    if (__any(mx > mst + 12.f)) {                                                           \
      const float mn = fmaxf(mst, mx);                                                      \
      const float alpha = __builtin_amdgcn_exp2f(mst - mn);                                 \
      mst = mn;                                                                             \
      lst *= alpha;                                                                         \
      O[0] *= alpha;                                                                        \
      O[1] *= alpha;                                                                        \
    }                                                                                       \
    float rs = 0.f;                                                                         \
    _Pragma("unroll") for (int kb = 0; kb < 2; ++kb)                                        \
      _Pragma("unroll") for (int r = 0; r < 16; ++r) {                                      \
        const float p = __builtin_amdgcn_exp2f(s[kb][r] - mst);                             \
        s[kb][r] = p;                                                                       \
        rs += p;                                                                            \
      }                                                                                     \
    rs += __shfl_xor(rs, 32);                                                               \
    lst += rs;                                                                              \
    unsigned w[16];                                                                         \
    _Pragma("unroll") for (int kb = 0; kb < 2; ++kb)                                        \
      _Pragma("unroll") for (int j2 = 0; j2 < 4; ++j2) {                                    \
        asm("v_cvt_pk_bf16_f32 %0, %1, %2"                                                  \
            : "=v"(w[kb * 8 + j2 * 2]) : "v"(s[kb][4 * j2]), "v"(s[kb][4 * j2 + 1]));       \
        asm("v_cvt_pk_bf16_f32 %0, %1, %2"                                                  \
            : "=v"(w[kb * 8 + j2 * 2 + 1]) : "v"(s[kb][4 * j2 + 2]), "v"(s[kb][4 * j2 + 3])); \
      }                                                                                     \
    unsigned recv[8];                                                                       \
    _Pragma("unroll") for (int cc = 0; cc < 4; ++cc)                                        \
      _Pragma("unroll") for (int m = 0; m < 2; ++m) {                                       \
        const unsigned send = H ? w[4 * cc + m] : w[4 * cc + 2 + m];                        \
        recv[cc * 2 + m] = (unsigned)__shfl_xor((int)send, 32);                             \
      }                                                                                     \
    _Pragma("unroll") for (int cc = 0; cc < 4; ++cc) {                                      \
      union { unsigned u[4]; bf16x8 v; } Bp;                                                \
      Bp.u[0] = H ? recv[2 * cc] : w[4 * cc];                                               \
      Bp.u[1] = H ? recv[2 * cc + 1] : w[4 * cc + 1];                                       \
      Bp.u[2] = H ? w[4 * cc + 2] : recv[2 * cc];                                           \
      Bp.u[3] = H ? w[4 * cc + 3] : recv[2 * cc + 1];                                       \
      O[0] = __builtin_amdgcn_mfma_f32_32x32x16_bf16(vf[0][cc], Bp.v, O[0], 0, 0, 0);       \
      O[1] = __builtin_amdgcn_mfma_f32_32x32x16_bf16(vf[1][cc], Bp.v, O[1], 0, 0, 0);       \
    }                                                                                       \
    __builtin_amdgcn_s_barrier();                                                           \
  }

  STAGE(t0, 0);
  int t = t0;
  for (; t + 2 <= tend; t += 2) {
    BODY(t, 0);
    BODY(t + 1, 1);
  }
  if (t < tend) BODY(t, 0);
#undef BODY
#undef STAGE

  if (DIRECT) {
    const float inv = 1.0f / lst;
    u16* orow = aout + (size_t)(q0 + lr) * 768 + h * 64;
#pragma unroll
    for (int da = 0; da < 2; ++da)
#pragma unroll
      for (int j2 = 0; j2 < 4; ++j2) {
        ushort4 st;
        st.x = f2bf(O[da][4 * j2 + 0] * inv);
        st.y = f2bf(O[da][4 * j2 + 1] * inv);
        st.z = f2bf(O[da][4 * j2 + 2] * inv);
        st.w = f2bf(O[da][4 * j2 + 3] * inv);
        *(ushort4*)(orow + 32 * da + 8 * j2 + H4) = st;
      }
  } else {
    const int slot = (h * 128 + qt) * 4 + c;
    u16* po = pO + (size_t)slot * 2048 + lr * 64;
#pragma unroll
    for (int da = 0; da < 2; ++da)
#pragma unroll
      for (int j2 = 0; j2 < 4; ++j2) {
        ushort4 st;
        st.x = f2bf(O[da][4 * j2 + 0]);
        st.y = f2bf(O[da][4 * j2 + 1]);
        st.z = f2bf(O[da][4 * j2 + 2]);
        st.w = f2bf(O[da][4 * j2 + 3]);
        *(ushort4*)(po + 32 * da + 8 * j2 + H4) = st;
      }
    if (H == 0) {
      float2 ml; ml.x = mst; ml.y = lst;
      *(float2*)(pml + (size_t)slot * 64 + lr * 2) = ml;
    }
  }
}

// combine partials: one block per (h, qt); thread = (row 0..31) x (dim-half 0..1)
__global__ __launch_bounds__(64) void combine(const u16* __restrict__ pO, const float* __restrict__ pml,
                                              u16* __restrict__ aout, int CHv) {
  const int bid = blockIdx.x;
  const int h = bid % 12, qt = bid / 12;
  const int nkt = (qt >> 1) + 1;
  const int nc = (nkt + CHv - 1) / CHv;
  const int sb = (h * 128 + qt) * 4;
  const int t = threadIdx.x;
  const int row = t & 31, H = t >> 5;

  float m[4], lw[4];
  float M = -__builtin_inff();
#pragma unroll
  for (int c = 0; c < 4; ++c)
    if (c < nc) {
      m[c] = pml[(size_t)(sb + c) * 64 + row * 2];
      M = fmaxf(M, m[c]);
    }
  float L = 0.f;
#pragma unroll
  for (int c = 0; c < 4; ++c)
    if (c < nc) {
      lw[c] = __builtin_amdgcn_exp2f(m[c] - M);
      L += pml[(size_t)(sb + c) * 64 + row * 2 + 1] * lw[c];
    }

  float acc[32] = {};
#pragma unroll
  for (int c = 0; c < 4; ++c)
    if (c < nc) {
      const u16* p = pO + (size_t)(sb + c) * 2048 + row * 64 + 32 * H;
      const float wgt = lw[c];
#pragma unroll
      for (int k = 0; k < 4; ++k) {
        bf16x8 v = *(const bf16x8*)(p + 8 * k);
#pragma unroll
        for (int e = 0; e < 8; ++e) acc[k * 8 + e] += (float)v[e] * wgt;
      }
    }

  const float inv = 1.0f / L;
  u16 ov[32];
#pragma unroll
  for (int d = 0; d < 32; ++d) ov[d] = f2bf(acc[d] * inv);
  u16* dst = aout + (size_t)(qt * 32 + row) * 768 + h * 64 + 32 * H;
#pragma unroll
  for (int k = 0; k < 4; ++k) *(uint4*)(dst + 8 * k) = *(const uint4*)(ov + 8 * k);
}

// ---------------- launch ----------------
extern "C" void kernel_launch(void* const* d_in, const int* in_sizes, int n_in,
                              void* d_out, int out_size, void* d_ws, size_t ws_size,
                              hipStream_t stream) {
  const float* x = (const float*)d_in[0];
  const float* w_attn = (const float*)d_in[1];
  const float* b_attn = (const float*)d_in[2];
  const float* w_proj = (const float*)d_in[3];
  const float* b_proj = (const float*)d_in[4];
  float* out = (float*)d_out;

  const int S = 4096, D = 768;
  u16* xb = (u16*)d_ws;                 // [4096][768]
  u16* wTa = xb + (size_t)S * D;        // [2304][768]
  u16* wTp = wTa + (size_t)3 * D * D;   // [768][768]
  u16* qkv = wTp + (size_t)D * D;       // [4096][2304]
  u16* abuf = qkv + (size_t)S * 3 * D;  // [4096][768]
  u16* vTb = abuf + (size_t)S * D;      // [12][64][4096]
  u16* pO = vTb + (size_t)12 * 64 * 4096;

  const size_t base_bytes = (size_t)(3145728 + 1769472 + 589824 + 9437184 + 3145728 + 3145728) * 2;
  const size_t need16 = base_bytes + (size_t)6144 * 2048 * 2 + (size_t)6144 * 64 * 4;

  cvt_bf16<<<(S * D) / 1024, 256, 0, stream>>>(x, xb, S * D);
  transpose_cvt<<<dim3((3 * D) / 32, D / 32), dim3(32, 8), 0, stream>>>(w_attn, wTa, D, 3 * D);
  transpose_cvt<<<dim3(D / 32, D / 32), dim3(32, 8), 0, stream>>>(w_proj, wTp, D, D);
  gemm_bt<1><<<dim3((3 * D) / 128, S / 128), 256, 0, stream>>>(xb, wTa, b_attn, qkv, S, 3 * D, D);
  vtrans<<<dim3(S / 64, 12), 256, 0, stream>>>(qkv, vTb);

  if (ws_size >= need16) {
    float* pml = (float*)(pO + (size_t)6144 * 2048);
    attn<16, 0><<<dim3(12 * 80), 256, 0, stream>>>(qkv, vTb, pO, pml, abuf);
    combine<<<dim3(12 * 128), 64, 0, stream>>>(pO, pml, abuf, 16);
  } else {
    attn<64, 1><<<dim3(12 * 32), 256, 0, stream>>>(qkv, vTb, abuf, (float*)abuf, abuf);
  }

  gemm_bt<0><<<dim3(D / 128, S / 128), 256, 0, stream>>>(abuf, wTp, b_proj, out, S, D, D);
}